// Round 10
// baseline (131.574 us; speedup 1.0000x reference)
//
#include <hip/hip_runtime.h>
#include <math.h>

#define BB 64
#define TT 2048
#define RNN 1024
#define EMB 512
#define ATTN 128
#define NF 32
#define KS 31
#define PADW 15

#define TIL 32            // t per block
#define CHT 8             // t per wave (= softmax chunk)
#define NCH (TT / CHT)    // 256 chunks per b

__device__ __forceinline__ float fast_tanh(float x) {
    float ax = fabsf(x);
    float e = __expf(-2.f * ax);
    float r = (1.f - e) * __builtin_amdgcn_rcpf(1.f + e);
    return copysignf(r, x);
}

// ---------------------------------------------------------------------------
// Kernel 1: pq[b][a] = sum_r h[b][r] * Wq[a][r]
// ---------------------------------------------------------------------------
__global__ __launch_bounds__(256) void pq_kernel(const float* __restrict__ h,
                                                 const float* __restrict__ Wq,
                                                 float* __restrict__ pq) {
    int b = blockIdx.x >> 2;
    int q = blockIdx.x & 3;
    __shared__ float s_h[RNN];
    for (int i = threadIdx.x; i < RNN; i += 256) s_h[i] = h[b * RNN + i];
    __syncthreads();

    int wave = threadIdx.x >> 6;
    int lane = threadIdx.x & 63;
#pragma unroll 2
    for (int j = 0; j < 8; ++j) {
        int a = q * 32 + wave * 8 + j;
        const float4* wq4 = (const float4*)(Wq + (size_t)a * RNN);
        float acc = 0.f;
#pragma unroll
        for (int i = 0; i < 4; ++i) {
            float4 w4 = wq4[lane + 64 * i];
            float4 h4 = *(const float4*)(s_h + 4 * (lane + 64 * i));
            acc += w4.x * h4.x + w4.y * h4.y + w4.z * h4.z + w4.w * h4.w;
        }
#pragma unroll
        for (int off = 32; off > 0; off >>= 1) acc += __shfl_xor(acc, off, 64);
        if (lane == 0) pq[b * ATTN + a] = acc;
    }
}

// ---------------------------------------------------------------------------
// Kernel 2 (fused v3): 32-t tile, 4 phases.
//   conv -> s_conv ; ploc GEMM -> s_ploc (uniform-broadcast LDS reads,
//   Wloc rows in regs) ; energy (lane owns a-pair, batched butterfly,
//   in-reg softmax over 8-t chunk) ; fused ctx partial.
// grid = B*64 = 4096, block = 256.
// ---------------------------------------------------------------------------
__global__ __launch_bounds__(256) void fused3_kernel(
    const float* __restrict__ pm,     // [B][T][ATTN]
    const float* __restrict__ awc,    // [B][2][T]
    const float* __restrict__ mem,    // [B][T][EMB]
    const unsigned char* __restrict__ mask,  // [B][T]
    const float* __restrict__ pq,     // [B][ATTN]
    const float* __restrict__ Wconv,  // [NF][2][KS]
    const float* __restrict__ Wloc,   // [ATTN][NF]
    const float* __restrict__ Wv,     // [ATTN]
    float* __restrict__ wp,           // [B][T] unnormalized exp
    float* __restrict__ ms,           // [B][NCH][2]
    float* __restrict__ cp)           // [B][NCH][EMB]
{
    int b = blockIdx.x >> 6;
    int blk = blockIdx.x & 63;
    int t0 = blk * TIL;
    int tid = threadIdx.x;
    int w = tid >> 6;
    int l = tid & 63;

    __shared__ __align__(16) float s_ploc[TIL][ATTN];   // 16 KB
    __shared__ __align__(16) float s_conv[TIL][40];     // 5 KB, 160B rows
    __shared__ float s_awc[2][TIL + 2 * PADW + 2];      // 2 x 64
    __shared__ float s_pq[ATTN];
    __shared__ float s_wv[ATTN];

    // ---- stage awc window + pq + Wv ----
    for (int i = tid; i < 2 * (TIL + 2 * PADW); i += 256) {
        int c = i / (TIL + 2 * PADW);
        int j = i % (TIL + 2 * PADW);
        int tg = t0 - PADW + j;
        s_awc[c][j] = (tg >= 0 && tg < TT) ? awc[((size_t)b * 2 + c) * TT + tg] : 0.f;
    }
    if (tid < ATTN) {
        s_pq[tid] = pq[b * ATTN + tid];
        s_wv[tid] = Wv[tid];
    }
    __syncthreads();

    // ---- phase 1: conv. thread = (t = tid&31, f-quad = tid>>5) ----
    {
        int t = tid & 31;
        int fq = tid >> 5;  // 0..7
        float a0 = 0.f, a1 = 0.f, a2 = 0.f, a3 = 0.f;
#pragma unroll
        for (int c = 0; c < 2; ++c) {
            const float* wc = Wconv + (size_t)((fq * 4) * 2 + c) * KS;
#pragma unroll
            for (int k = 0; k < KS; ++k) {
                float av = s_awc[c][t + k];  // broadcast pairs, conflict-free
                a0 += av * wc[k];
                a1 += av * wc[2 * KS + k];
                a2 += av * wc[4 * KS + k];
                a3 += av * wc[6 * KS + k];
            }
        }
        s_conv[t][fq * 4 + 0] = a0;
        s_conv[t][fq * 4 + 1] = a1;
        s_conv[t][fq * 4 + 2] = a2;
        s_conv[t][fq * 4 + 3] = a3;
    }
    __syncthreads();

    // ---- phase 2: ploc GEMM. thread = (a = tid&127, t-group = tid>>7) ----
    {
        int a = tid & 127;
        int tg = tid >> 7;  // 0..1, 16 t each
        const float4* wlr = (const float4*)(Wloc + (size_t)a * NF);  // L1-resident
        float4 w0 = wlr[0], w1 = wlr[1], w2 = wlr[2], w3 = wlr[3];
        float4 w4 = wlr[4], w5 = wlr[5], w6 = wlr[6], w7 = wlr[7];
#pragma unroll
        for (int tt = 0; tt < 16; ++tt) {
            int t = tg * 16 + tt;
            const float4* cv = (const float4*)&s_conv[t][0];  // uniform broadcast
            float4 c0 = cv[0], c1 = cv[1], c2 = cv[2], c3 = cv[3];
            float4 c4 = cv[4], c5 = cv[5], c6 = cv[6], c7 = cv[7];
            float acc;
            acc  = c0.x * w0.x + c0.y * w0.y + c0.z * w0.z + c0.w * w0.w;
            acc += c1.x * w1.x + c1.y * w1.y + c1.z * w1.z + c1.w * w1.w;
            acc += c2.x * w2.x + c2.y * w2.y + c2.z * w2.z + c2.w * w2.w;
            acc += c3.x * w3.x + c3.y * w3.y + c3.z * w3.z + c3.w * w3.w;
            acc += c4.x * w4.x + c4.y * w4.y + c4.z * w4.z + c4.w * w4.w;
            acc += c5.x * w5.x + c5.y * w5.y + c5.z * w5.z + c5.w * w5.w;
            acc += c6.x * w6.x + c6.y * w6.y + c6.z * w6.z + c6.w * w6.w;
            acc += c7.x * w7.x + c7.y * w7.y + c7.z * w7.z + c7.w * w7.w;
            s_ploc[t][a] = acc;  // consecutive lanes -> 2-way (free)
        }
    }
    __syncthreads();

    // ---- phase 3: energy. wave owns 8 t (t = w*8+i), lane owns a-pair ----
    float pq0 = s_pq[l], pq1 = s_pq[l + 64];
    float wv0 = s_wv[l], wv1 = s_wv[l + 64];

    float pA[CHT], pB[CHT];
#pragma unroll
    for (int i = 0; i < CHT; ++i) {
        const float* r = pm + ((size_t)b * TT + t0 + w * CHT + i) * ATTN;
        pA[i] = r[l];        // coalesced 256B
        pB[i] = r[l + 64];
    }
    float e[CHT];
#pragma unroll
    for (int i = 0; i < CHT; ++i) {
        int t = w * CHT + i;
        float v0 = pq0 + pA[i] + s_ploc[t][l];        // 2-way (free)
        float v1 = pq1 + pB[i] + s_ploc[t][l + 64];
        e[i] = wv0 * fast_tanh(v0) + wv1 * fast_tanh(v1);
    }
    // batched butterfly: 6 rounds x 8 independent shuffles
#pragma unroll
    for (int off = 32; off > 0; off >>= 1)
#pragma unroll
        for (int i = 0; i < CHT; ++i) e[i] += __shfl_xor(e[i], off, 64);

    // mask (2 uniform words)
    {
        const unsigned int* mk = (const unsigned int*)(mask + (size_t)b * TT + t0 + w * CHT);
        unsigned int m0 = mk[0], m1 = mk[1];
#pragma unroll
        for (int j = 0; j < 4; ++j) {
            if ((m0 >> (8 * j)) & 0xff) e[j] = -1e30f;
            if ((m1 >> (8 * j)) & 0xff) e[4 + j] = -1e30f;
        }
    }

    // in-register chunk softmax over 8 t
    float m = e[0];
#pragma unroll
    for (int i = 1; i < CHT; ++i) m = fmaxf(m, e[i]);
    float p[CHT], s = 0.f;
#pragma unroll
    for (int i = 0; i < CHT; ++i) {
        p[i] = __expf(e[i] - m);
        s += p[i];
    }
    int ch = blk * 4 + w;  // 0..255
    if (l == 0) {
        ms[((size_t)b * NCH + ch) * 2 + 0] = m;
        ms[((size_t)b * NCH + ch) * 2 + 1] = s;
    }
    {
        float pv = p[0];
#pragma unroll
        for (int i = 1; i < CHT; ++i)
            if (l == i) pv = p[i];
        if (l < CHT) wp[(size_t)b * TT + t0 + w * CHT + l] = pv;
    }

    // ---- phase 4: fused ctx partial over wave's 8 t ----
    float4 A0 = {0.f, 0.f, 0.f, 0.f}, A1 = {0.f, 0.f, 0.f, 0.f};
    const float4* m4 = (const float4*)(mem + ((size_t)b * TT + t0 + w * CHT) * EMB);
#pragma unroll
    for (int i = 0; i < CHT; ++i) {
        float pv = p[i];
        float4 v0 = m4[(size_t)i * (EMB / 4) + l];
        float4 v1 = m4[(size_t)i * (EMB / 4) + 64 + l];
        A0.x += pv * v0.x; A0.y += pv * v0.y; A0.z += pv * v0.z; A0.w += pv * v0.w;
        A1.x += pv * v1.x; A1.y += pv * v1.y; A1.z += pv * v1.z; A1.w += pv * v1.w;
    }
    float4* cp4 = (float4*)(cp + ((size_t)b * NCH + ch) * EMB);
    cp4[l] = A0;
    cp4[64 + l] = A1;
}

// ---------------------------------------------------------------------------
// Kernel 3: combine. grid = B, block = 256.
// ---------------------------------------------------------------------------
__global__ __launch_bounds__(256) void combine_kernel(
    const float* __restrict__ wp, const float* __restrict__ ms,
    const float* __restrict__ cp, float* __restrict__ ctx,
    float* __restrict__ wts) {
    int b = blockIdx.x;
    int tid = threadIdx.x;
    __shared__ float s_m[NCH], s_s[NCH], s_scale[NCH];
    if (tid < NCH) {
        s_m[tid] = ms[((size_t)b * NCH + tid) * 2 + 0];
        s_s[tid] = ms[((size_t)b * NCH + tid) * 2 + 1];
    }
    __syncthreads();
    float M = -1e30f;
#pragma unroll 8
    for (int c = 0; c < NCH; ++c) M = fmaxf(M, s_m[c]);
    float S = 0.f;
#pragma unroll 8
    for (int c = 0; c < NCH; ++c) S += s_s[c] * __expf(s_m[c] - M);
    float invS = 1.f / S;
    if (tid < NCH) s_scale[tid] = __expf(s_m[tid] - M) * invS;
    __syncthreads();

    {
        float2 acc = {0.f, 0.f};
        const float2* cp2 = (const float2*)(cp + (size_t)b * NCH * EMB);
#pragma unroll 8
        for (int c = 0; c < NCH; ++c) {
            float sc = s_scale[c];
            float2 v = cp2[(size_t)c * (EMB / 2) + tid];
            acc.x += sc * v.x;
            acc.y += sc * v.y;
        }
        ((float2*)(ctx + (size_t)b * EMB))[tid] = acc;
    }
#pragma unroll
    for (int i = 0; i < 8; ++i) {
        int t = i * 256 + tid;
        wts[(size_t)b * TT + t] = wp[(size_t)b * TT + t] * s_scale[t >> 3];
    }
}

// ---------------------------------------------------------------------------
extern "C" void kernel_launch(void* const* d_in, const int* in_sizes, int n_in,
                              void* d_out, int out_size, void* d_ws, size_t ws_size,
                              hipStream_t stream) {
    const float* h    = (const float*)d_in[0];
    const float* mem  = (const float*)d_in[1];
    const float* pmem = (const float*)d_in[2];
    const float* awc  = (const float*)d_in[3];
    const unsigned char* mask = (const unsigned char*)d_in[4];
    const float* Wq   = (const float*)d_in[5];
    const float* Wcv  = (const float*)d_in[6];
    const float* Wloc = (const float*)d_in[7];
    const float* Wv   = (const float*)d_in[8];

    float* out = (float*)d_out;
    float* ctx = out;             // [B][EMB]
    float* wts = out + BB * EMB;  // [B][T]

    float* ws = (float*)d_ws;
    float* pq = ws;                 // [B][ATTN]
    float* wp = pq + BB * ATTN;     // [B][T]
    float* ms = wp + BB * TT;       // [B][NCH][2]
    float* cp = ms + BB * NCH * 2;  // [B][NCH][EMB]

    pq_kernel<<<BB * 4, 256, 0, stream>>>(h, Wq, pq);
    fused3_kernel<<<BB * 64, 256, 0, stream>>>(pmem, awc, mem, mask, pq, Wcv,
                                               Wloc, Wv, wp, ms, cp);
    combine_kernel<<<BB, 256, 0, stream>>>(wp, ms, cp, ctx, wts);
}

// Round 11
// 130.880 us; speedup vs baseline: 1.0053x; 1.0053x over previous
//
#include <hip/hip_runtime.h>
#include <math.h>

#define BB 64
#define TT 2048
#define RNN 1024
#define EMB 512
#define ATTN 128
#define NF 32
#define KS 31
#define PADW 15

#define TIL 32            // t per block
#define CHT 8             // t per wave (= softmax chunk)
#define NCH (TT / CHT)    // 256 chunks per b

__device__ __forceinline__ float fast_tanh(float x) {
    float ax = fabsf(x);
    float e = __expf(-2.f * ax);
    float r = (1.f - e) * __builtin_amdgcn_rcpf(1.f + e);
    return copysignf(r, x);
}

// ---------------------------------------------------------------------------
// Kernel 1: pq[b][a] = sum_r h[b][r] * Wq[a][r]
// ---------------------------------------------------------------------------
__global__ __launch_bounds__(256) void pq_kernel(const float* __restrict__ h,
                                                 const float* __restrict__ Wq,
                                                 float* __restrict__ pq) {
    int b = blockIdx.x >> 2;
    int q = blockIdx.x & 3;
    __shared__ float s_h[RNN];
    for (int i = threadIdx.x; i < RNN; i += 256) s_h[i] = h[b * RNN + i];
    __syncthreads();

    int wave = threadIdx.x >> 6;
    int lane = threadIdx.x & 63;
#pragma unroll 2
    for (int j = 0; j < 8; ++j) {
        int a = q * 32 + wave * 8 + j;
        const float4* wq4 = (const float4*)(Wq + (size_t)a * RNN);
        float acc = 0.f;
#pragma unroll
        for (int i = 0; i < 4; ++i) {
            float4 w4 = wq4[lane + 64 * i];
            float4 h4 = *(const float4*)(s_h + 4 * (lane + 64 * i));
            acc += w4.x * h4.x + w4.y * h4.y + w4.z * h4.z + w4.w * h4.w;
        }
#pragma unroll
        for (int off = 32; off > 0; off >>= 1) acc += __shfl_xor(acc, off, 64);
        if (lane == 0) pq[b * ATTN + a] = acc;
    }
}

// ---------------------------------------------------------------------------
// Kernel 2 (fused v3 + T14 prefetch): 32-t tile, 4 phases.
//   conv -> s_conv ; ploc GEMM -> s_ploc ; [PREFETCH mem rows to regs] ->
//   energy (batched butterfly, in-reg softmax) ; ctx from regs (pure FMA).
// grid = B*64 = 4096, block = 256.
// ---------------------------------------------------------------------------
__global__ __launch_bounds__(256) void fused3_kernel(
    const float* __restrict__ pm,     // [B][T][ATTN]
    const float* __restrict__ awc,    // [B][2][T]
    const float* __restrict__ mem,    // [B][T][EMB]
    const unsigned char* __restrict__ mask,  // [B][T]
    const float* __restrict__ pq,     // [B][ATTN]
    const float* __restrict__ Wconv,  // [NF][2][KS]
    const float* __restrict__ Wloc,   // [ATTN][NF]
    const float* __restrict__ Wv,     // [ATTN]
    float* __restrict__ wp,           // [B][T] unnormalized exp
    float* __restrict__ ms,           // [B][NCH][2]
    float* __restrict__ cp)           // [B][NCH][EMB]
{
    int b = blockIdx.x >> 6;
    int blk = blockIdx.x & 63;
    int t0 = blk * TIL;
    int tid = threadIdx.x;
    int w = tid >> 6;
    int l = tid & 63;

    __shared__ __align__(16) float s_ploc[TIL][ATTN];   // 16 KB
    __shared__ __align__(16) float s_conv[TIL][40];     // 5 KB, 160B rows
    __shared__ float s_awc[2][TIL + 2 * PADW + 2];      // 2 x 64
    __shared__ float s_pq[ATTN];
    __shared__ float s_wv[ATTN];

    // ---- stage awc window + pq + Wv ----
    for (int i = tid; i < 2 * (TIL + 2 * PADW); i += 256) {
        int c = i / (TIL + 2 * PADW);
        int j = i % (TIL + 2 * PADW);
        int tg = t0 - PADW + j;
        s_awc[c][j] = (tg >= 0 && tg < TT) ? awc[((size_t)b * 2 + c) * TT + tg] : 0.f;
    }
    if (tid < ATTN) {
        s_pq[tid] = pq[b * ATTN + tid];
        s_wv[tid] = Wv[tid];
    }
    __syncthreads();

    // ---- phase 1: conv. thread = (t = tid&31, f-quad = tid>>5) ----
    {
        int t = tid & 31;
        int fq = tid >> 5;  // 0..7
        float a0 = 0.f, a1 = 0.f, a2 = 0.f, a3 = 0.f;
#pragma unroll
        for (int c = 0; c < 2; ++c) {
            const float* wc = Wconv + (size_t)((fq * 4) * 2 + c) * KS;
#pragma unroll
            for (int k = 0; k < KS; ++k) {
                float av = s_awc[c][t + k];  // broadcast pairs, conflict-free
                a0 += av * wc[k];
                a1 += av * wc[2 * KS + k];
                a2 += av * wc[4 * KS + k];
                a3 += av * wc[6 * KS + k];
            }
        }
        s_conv[t][fq * 4 + 0] = a0;
        s_conv[t][fq * 4 + 1] = a1;
        s_conv[t][fq * 4 + 2] = a2;
        s_conv[t][fq * 4 + 3] = a3;
    }
    __syncthreads();

    // ---- phase 2: ploc GEMM. thread = (a = tid&127, t-group = tid>>7) ----
    {
        int a = tid & 127;
        int tg = tid >> 7;  // 0..1, 16 t each
        const float4* wlr = (const float4*)(Wloc + (size_t)a * NF);  // L1-resident
        float4 w0 = wlr[0], w1 = wlr[1], w2 = wlr[2], w3 = wlr[3];
        float4 w4 = wlr[4], w5 = wlr[5], w6 = wlr[6], w7 = wlr[7];
#pragma unroll
        for (int tt = 0; tt < 16; ++tt) {
            int t = tg * 16 + tt;
            const float4* cv = (const float4*)&s_conv[t][0];  // uniform broadcast
            float4 c0 = cv[0], c1 = cv[1], c2 = cv[2], c3 = cv[3];
            float4 c4 = cv[4], c5 = cv[5], c6 = cv[6], c7 = cv[7];
            float acc;
            acc  = c0.x * w0.x + c0.y * w0.y + c0.z * w0.z + c0.w * w0.w;
            acc += c1.x * w1.x + c1.y * w1.y + c1.z * w1.z + c1.w * w1.w;
            acc += c2.x * w2.x + c2.y * w2.y + c2.z * w2.z + c2.w * w2.w;
            acc += c3.x * w3.x + c3.y * w3.y + c3.z * w3.z + c3.w * w3.w;
            acc += c4.x * w4.x + c4.y * w4.y + c4.z * w4.z + c4.w * w4.w;
            acc += c5.x * w5.x + c5.y * w5.y + c5.z * w5.z + c5.w * w5.w;
            acc += c6.x * w6.x + c6.y * w6.y + c6.z * w6.z + c6.w * w6.w;
            acc += c7.x * w7.x + c7.y * w7.y + c7.z * w7.z + c7.w * w7.w;
            s_ploc[t][a] = acc;  // consecutive lanes -> 2-way (free)
        }
    }
    __syncthreads();

    // ---- T14 prefetch: issue ctx mem loads FIRST (oldest in VMEM queue) ----
    float4 mv0[CHT], mv1[CHT];
    {
        const float4* m4 = (const float4*)(mem + ((size_t)b * TT + t0 + w * CHT) * EMB);
#pragma unroll
        for (int i = 0; i < CHT; ++i) {
            mv0[i] = m4[(size_t)i * (EMB / 4) + l];
            mv1[i] = m4[(size_t)i * (EMB / 4) + 64 + l];
        }
    }

    // ---- phase 3: energy. wave owns 8 t, lane owns a-pair ----
    float pq0 = s_pq[l], pq1 = s_pq[l + 64];
    float wv0 = s_wv[l], wv1 = s_wv[l + 64];

    float pA[CHT], pB[CHT];
#pragma unroll
    for (int i = 0; i < CHT; ++i) {
        const float* r = pm + ((size_t)b * TT + t0 + w * CHT + i) * ATTN;
        pA[i] = r[l];        // coalesced; younger than mem prefetch
        pB[i] = r[l + 64];
    }
    float e[CHT];
#pragma unroll
    for (int i = 0; i < CHT; ++i) {
        int t = w * CHT + i;
        float v0 = pq0 + pA[i] + s_ploc[t][l];        // 2-way (free)
        float v1 = pq1 + pB[i] + s_ploc[t][l + 64];
        e[i] = wv0 * fast_tanh(v0) + wv1 * fast_tanh(v1);
    }
    // batched butterfly: 6 rounds x 8 independent shuffles
#pragma unroll
    for (int off = 32; off > 0; off >>= 1)
#pragma unroll
        for (int i = 0; i < CHT; ++i) e[i] += __shfl_xor(e[i], off, 64);

    // mask (2 uniform words)
    {
        const unsigned int* mk = (const unsigned int*)(mask + (size_t)b * TT + t0 + w * CHT);
        unsigned int m0 = mk[0], m1 = mk[1];
#pragma unroll
        for (int j = 0; j < 4; ++j) {
            if ((m0 >> (8 * j)) & 0xff) e[j] = -1e30f;
            if ((m1 >> (8 * j)) & 0xff) e[4 + j] = -1e30f;
        }
    }

    // in-register chunk softmax over 8 t
    float m = e[0];
#pragma unroll
    for (int i = 1; i < CHT; ++i) m = fmaxf(m, e[i]);
    float p[CHT], s = 0.f;
#pragma unroll
    for (int i = 0; i < CHT; ++i) {
        p[i] = __expf(e[i] - m);
        s += p[i];
    }
    int ch = blk * 4 + w;  // 0..255
    if (l == 0) {
        ms[((size_t)b * NCH + ch) * 2 + 0] = m;
        ms[((size_t)b * NCH + ch) * 2 + 1] = s;
    }
    {
        float pv = p[0];
#pragma unroll
        for (int i = 1; i < CHT; ++i)
            if (l == i) pv = p[i];
        if (l < CHT) wp[(size_t)b * TT + t0 + w * CHT + l] = pv;
    }

    // ---- phase 4: ctx from prefetched regs (pure FMA) ----
    float4 A0 = {0.f, 0.f, 0.f, 0.f}, A1 = {0.f, 0.f, 0.f, 0.f};
#pragma unroll
    for (int i = 0; i < CHT; ++i) {
        float pv = p[i];
        A0.x += pv * mv0[i].x; A0.y += pv * mv0[i].y;
        A0.z += pv * mv0[i].z; A0.w += pv * mv0[i].w;
        A1.x += pv * mv1[i].x; A1.y += pv * mv1[i].y;
        A1.z += pv * mv1[i].z; A1.w += pv * mv1[i].w;
    }
    float4* cp4 = (float4*)(cp + ((size_t)b * NCH + ch) * EMB);
    cp4[l] = A0;
    cp4[64 + l] = A1;
}

// ---------------------------------------------------------------------------
// Kernel 3: combine. grid = B, block = 256.
// ---------------------------------------------------------------------------
__global__ __launch_bounds__(256) void combine_kernel(
    const float* __restrict__ wp, const float* __restrict__ ms,
    const float* __restrict__ cp, float* __restrict__ ctx,
    float* __restrict__ wts) {
    int b = blockIdx.x;
    int tid = threadIdx.x;
    __shared__ float s_m[NCH], s_s[NCH], s_scale[NCH];
    if (tid < NCH) {
        s_m[tid] = ms[((size_t)b * NCH + tid) * 2 + 0];
        s_s[tid] = ms[((size_t)b * NCH + tid) * 2 + 1];
    }
    __syncthreads();
    float M = -1e30f;
#pragma unroll 8
    for (int c = 0; c < NCH; ++c) M = fmaxf(M, s_m[c]);
    float S = 0.f;
#pragma unroll 8
    for (int c = 0; c < NCH; ++c) S += s_s[c] * __expf(s_m[c] - M);
    float invS = 1.f / S;
    if (tid < NCH) s_scale[tid] = __expf(s_m[tid] - M) * invS;
    __syncthreads();

    {
        float2 acc = {0.f, 0.f};
        const float2* cp2 = (const float2*)(cp + (size_t)b * NCH * EMB);
#pragma unroll 8
        for (int c = 0; c < NCH; ++c) {
            float sc = s_scale[c];
            float2 v = cp2[(size_t)c * (EMB / 2) + tid];
            acc.x += sc * v.x;
            acc.y += sc * v.y;
        }
        ((float2*)(ctx + (size_t)b * EMB))[tid] = acc;
    }
#pragma unroll
    for (int i = 0; i < 8; ++i) {
        int t = i * 256 + tid;
        wts[(size_t)b * TT + t] = wp[(size_t)b * TT + t] * s_scale[t >> 3];
    }
}

// ---------------------------------------------------------------------------
extern "C" void kernel_launch(void* const* d_in, const int* in_sizes, int n_in,
                              void* d_out, int out_size, void* d_ws, size_t ws_size,
                              hipStream_t stream) {
    const float* h    = (const float*)d_in[0];
    const float* mem  = (const float*)d_in[1];
    const float* pmem = (const float*)d_in[2];
    const float* awc  = (const float*)d_in[3];
    const unsigned char* mask = (const unsigned char*)d_in[4];
    const float* Wq   = (const float*)d_in[5];
    const float* Wcv  = (const float*)d_in[6];
    const float* Wloc = (const float*)d_in[7];
    const float* Wv   = (const float*)d_in[8];

    float* out = (float*)d_out;
    float* ctx = out;             // [B][EMB]
    float* wts = out + BB * EMB;  // [B][T]

    float* ws = (float*)d_ws;
    float* pq = ws;                 // [B][ATTN]
    float* wp = pq + BB * ATTN;     // [B][T]
    float* ms = wp + BB * TT;       // [B][NCH][2]
    float* cp = ms + BB * NCH * 2;  // [B][NCH][EMB]

    pq_kernel<<<BB * 4, 256, 0, stream>>>(h, Wq, pq);
    fused3_kernel<<<BB * 64, 256, 0, stream>>>(pmem, awc, mem, mask, pq, Wcv,
                                               Wloc, Wv, wp, ms, cp);
    combine_kernel<<<BB, 256, 0, stream>>>(wp, ms, cp, ctx, wts);
}